// Round 9
// baseline (151.027 us; speedup 1.0000x reference)
//
#include <hip/hip_runtime.h>

// MultiHashEncoding: 2-level dense grid trilinear interpolation, spatially
// binned for L2 locality.
//
// r8 evidence: main kernel 88us, FETCH 37.8MB (locality good), occupancy
// 68%->36% (CP dispatch-rate cap: 15625 fast blocks), VGPR=56 (16-load batch
// collapsed to ~4 in flight). r9: 4 points/quad, two-deep software pipeline
// (issue pt k+1's 16 gathers before consuming pt k) -> 32 loads in flight,
// 4x fewer, 4x longer blocks.
//
// Reference semantics (bit-exact corners): corner = floor(coords + OFFSET)
// with f32 add BEFORE floor; clip to [0,dim-1]; weight from CLIPPED corner.

typedef float floatx4 __attribute__((ext_vector_type(4)));

#define KXB 8
#define KYB 17
#define KZB 31
#define NBINS (KXB * KYB * KZB)          // 4216
#define SCAN_T 256
#define CHUNK ((NBINS + SCAN_T - 1) / SCAN_T)  // 17

__device__ __forceinline__ int point_key(float px, float py, float pz) {
    int ix = (int)(px * 15.0f);  ix = min(max(ix, 0), 15);
    int iy = (int)(py * 135.0f); iy = min(max(iy, 0), 135);
    int iz = (int)(pz * 240.0f); iz = min(max(iz, 0), 240);
    return ((ix >> 1) * KYB + (iy >> 3)) * KZB + (iz >> 3);
}

__device__ __forceinline__ void load4pts(const float* __restrict__ pts, int i4,
                                         float px[4], float py[4], float pz[4]) {
    const floatx4* v = (const floatx4*)(pts + (size_t)i4 * 3);
    const floatx4 a = v[0], b = v[1], c = v[2];
    px[0] = a.x; py[0] = a.y; pz[0] = a.z;
    px[1] = a.w; py[1] = b.x; pz[1] = b.y;
    px[2] = b.z; py[2] = b.w; pz[2] = c.x;
    px[3] = c.y; py[3] = c.z; pz[3] = c.w;
}

// ---------------- pass 1: keys + rank (one atomic) ----------------
__global__ __launch_bounds__(256)
void k_hist(const float* __restrict__ pts, int n,
            unsigned* __restrict__ keys, unsigned* __restrict__ rank,
            unsigned* __restrict__ hist) {
    const int i4 = (blockIdx.x * blockDim.x + threadIdx.x) * 4;
    if (i4 >= n) return;
    if (i4 + 3 < n) {
        float px[4], py[4], pz[4];
        load4pts(pts, i4, px, py, pz);
        unsigned k[4], r[4];
#pragma unroll
        for (int j = 0; j < 4; ++j) {
            k[j] = (unsigned)point_key(px[j], py[j], pz[j]);
            r[j] = atomicAdd(&hist[k[j]], 1u);
        }
        *(uint4*)(keys + i4) = make_uint4(k[0], k[1], k[2], k[3]);
        *(uint4*)(rank + i4) = make_uint4(r[0], r[1], r[2], r[3]);
    } else {
        for (int j = 0; j < 4 && i4 + j < n; ++j) {
            const size_t b = (size_t)(i4 + j) * 3;
            const unsigned k = (unsigned)point_key(pts[b], pts[b+1], pts[b+2]);
            keys[i4 + j] = k;
            rank[i4 + j] = atomicAdd(&hist[k], 1u);
        }
    }
}

// ---------------- pass 2: exclusive scan (one block) ----------------
__global__ __launch_bounds__(SCAN_T)
void k_scan(const unsigned* __restrict__ hist, unsigned* __restrict__ base) {
    __shared__ unsigned part[SCAN_T];
    const int t = threadIdx.x;
    unsigned local[CHUNK];
    unsigned s = 0;
#pragma unroll
    for (int j = 0; j < CHUNK; ++j) {
        const int idx = t * CHUNK + j;
        const unsigned v = (idx < NBINS) ? hist[idx] : 0u;
        local[j] = s;
        s += v;
    }
    part[t] = s;
    __syncthreads();
    for (int off = 1; off < SCAN_T; off <<= 1) {
        unsigned y = 0;
        if (t >= off) y = part[t - off];
        __syncthreads();
        if (t >= off) part[t] += y;
        __syncthreads();
    }
    const unsigned b = part[t] - s;
#pragma unroll
    for (int j = 0; j < CHUNK; ++j) {
        const int idx = t * CHUNK + j;
        if (idx < NBINS) base[idx] = b + local[j];
    }
}

// ---------------- pass 3: atomic-free scatter ----------------
__global__ __launch_bounds__(256)
void k_scatter(const float* __restrict__ pts, int n,
               const unsigned* __restrict__ keys, const unsigned* __restrict__ rank,
               const unsigned* __restrict__ base, floatx4* __restrict__ sorted) {
    const int i4 = (blockIdx.x * blockDim.x + threadIdx.x) * 4;
    if (i4 >= n) return;
    if (i4 + 3 < n) {
        float px[4], py[4], pz[4];
        load4pts(pts, i4, px, py, pz);
        const uint4 k = *(const uint4*)(keys + i4);
        const uint4 r = *(const uint4*)(rank + i4);
        const unsigned kk[4] = { k.x, k.y, k.z, k.w };
        const unsigned rr[4] = { r.x, r.y, r.z, r.w };
#pragma unroll
        for (int j = 0; j < 4; ++j) {
            const unsigned pos = base[kk[j]] + rr[j];
            floatx4 rec = { px[j], py[j], pz[j], __int_as_float(i4 + j) };
            sorted[pos] = rec;
        }
    } else {
        for (int j = 0; j < 4 && i4 + j < n; ++j) {
            const size_t b = (size_t)(i4 + j) * 3;
            const unsigned pos = base[keys[i4 + j]] + rank[i4 + j];
            floatx4 rec = { pts[b], pts[b+1], pts[b+2], __int_as_float(i4 + j) };
            sorted[pos] = rec;
        }
    }
}

// ---------------- main compute ----------------
template<int T, int H, int W>
__device__ __forceinline__ void level_setup(float px, float py, float pz, int dbase,
                                            int* __restrict__ off,   // [8]
                                            float* __restrict__ w) { // [8]
    const float cx = px * (float)(T - 1);
    const float cy = py * (float)(H - 1);
    const float cz = pz * (float)(W - 1);
    float gx[2] = { floorf(cx), floorf(cx + 1.0f) };
    float gy[2] = { floorf(cy), floorf(cy + 1.0f) };
    float gz[2] = { floorf(cz), floorf(cz + 1.0f) };
    float wx[2], wy[2], wz[2];
    int   xo[2], yo[2], zo[2];
#pragma unroll
    for (int b = 0; b < 2; ++b) {
        gx[b] = fminf(fmaxf(gx[b], 0.0f), (float)(T - 1));
        gy[b] = fminf(fmaxf(gy[b], 0.0f), (float)(H - 1));
        gz[b] = fminf(fmaxf(gz[b], 0.0f), (float)(W - 1));
        wx[b] = 1.0f - fabsf(gx[b] - cx);
        wy[b] = 1.0f - fabsf(gy[b] - cy);
        wz[b] = 1.0f - fabsf(gz[b] - cz);
        xo[b] = (int)gx[b] * (H * W * 16);
        yo[b] = (int)gy[b] * (W * 16);
        zo[b] = (int)gz[b] * 16 + dbase;
    }
    float wyz[4];
    int   yzo[4];
#pragma unroll
    for (int j = 0; j < 2; ++j)
#pragma unroll
        for (int k = 0; k < 2; ++k) {
            wyz[2 * j + k] = wy[j] * wz[k];
            yzo[2 * j + k] = yo[j] + zo[k];
        }
#pragma unroll
    for (int c = 0; c < 8; ++c) {
        const int i = (c >> 2) & 1, jk = c & 3;
        w[c]   = wx[i] * wyz[jk];
        off[c] = xo[i] + yzo[jk];
    }
}

struct PtState {
    float   w0[8], w1[8];
    floatx4 v0[8], v1[8];
    int     orig;
};

__device__ __forceinline__ void pt_issue(floatx4 rec, int d,
                                         const float* __restrict__ emb0,
                                         const float* __restrict__ emb1,
                                         PtState& s) {
    int o0[8], o1[8];
    level_setup<16, 136, 241>(rec.x, rec.y, rec.z, d, o0, s.w0);
    level_setup<9, 69, 121>(rec.x, rec.y, rec.z, d, o1, s.w1);
    s.orig = __float_as_int(rec.w);
#pragma unroll
    for (int c = 0; c < 8; ++c) s.v0[c] = *(const floatx4*)(emb0 + o0[c]);
#pragma unroll
    for (int c = 0; c < 8; ++c) s.v1[c] = *(const floatx4*)(emb1 + o1[c]);
}

__device__ __forceinline__ void pt_consume(const PtState& s, int d,
                                           float* __restrict__ out) {
    floatx4 a0 = {0.f, 0.f, 0.f, 0.f}, a1 = {0.f, 0.f, 0.f, 0.f};
#pragma unroll
    for (int c = 0; c < 8; ++c) a0 += s.w0[c] * s.v0[c];
#pragma unroll
    for (int c = 0; c < 8; ++c) a1 += s.w1[c] * s.v1[c];
    float* row = out + (size_t)s.orig * 32 + d;
    __builtin_nontemporal_store(a0, (floatx4*)row);
    __builtin_nontemporal_store(a1, (floatx4*)(row + 16));
}

// 4 lanes = 1 quad; each quad processes 4 consecutive sorted points with a
// two-deep pipeline: issue gathers for pt k+1 before consuming pt k.
__global__ __launch_bounds__(256)
void k_main_sorted(const floatx4* __restrict__ sorted,
                   const float* __restrict__ emb0,
                   const float* __restrict__ emb1,
                   float* __restrict__ out, int n) {
    // bijective XCD swizzle (m204 form), NXCD=8
    const int nwg = gridDim.x;
    const int q = nwg >> 3, r = nwg & 7;
    const int xcd = blockIdx.x & 7, ib = blockIdx.x >> 3;
    const int wg = (xcd < r ? xcd * (q + 1) : r * (q + 1) + (xcd - r) * q) + ib;

    const int g = wg * blockDim.x + threadIdx.x;
    const int quad = g >> 2;
    const int d = (g & 3) * 4;
    const int p0 = quad * 4;
    if (p0 >= n) return;

    floatx4 rec[4];
#pragma unroll
    for (int k = 0; k < 4; ++k) rec[k] = sorted[min(p0 + k, n - 1)];

    PtState sA, sB;
    pt_issue(rec[0], d, emb0, emb1, sA);
    pt_issue(rec[1], d, emb0, emb1, sB);
    __builtin_amdgcn_sched_barrier(0);
    pt_consume(sA, d, out);                       // pt0 (p0 < n guaranteed)
    pt_issue(rec[2], d, emb0, emb1, sA);
    __builtin_amdgcn_sched_barrier(0);
    if (p0 + 1 < n) pt_consume(sB, d, out);       // pt1
    pt_issue(rec[3], d, emb0, emb1, sB);
    __builtin_amdgcn_sched_barrier(0);
    if (p0 + 2 < n) pt_consume(sA, d, out);       // pt2
    if (p0 + 3 < n) pt_consume(sB, d, out);       // pt3
}

// fallback (no workspace)
__global__ __launch_bounds__(256)
void k_main_plain(const float* __restrict__ pts,
                  const float* __restrict__ emb0,
                  const float* __restrict__ emb1,
                  float* __restrict__ out, int n) {
    const int g = blockIdx.x * blockDim.x + threadIdx.x;
    const int p = g >> 2;
    const int d = (g & 3) * 4;
    if (p >= n) return;
    const size_t b = (size_t)p * 3;
    floatx4 rec = { pts[b], pts[b + 1], pts[b + 2], __int_as_float(p) };
    PtState s;
    pt_issue(rec, d, emb0, emb1, s);
    pt_consume(s, d, out);
}

extern "C" void kernel_launch(void* const* d_in, const int* in_sizes, int n_in,
                              void* d_out, int out_size, void* d_ws, size_t ws_size,
                              hipStream_t stream) {
    const float* pts  = (const float*)d_in[0];
    const float* emb0 = (const float*)d_in[1];
    const float* emb1 = (const float*)d_in[2];
    float* out = (float*)d_out;
    const int n = in_sizes[0] / 3;

    const int block = 256;
    const int n4      = (n + 3) / 4;
    const int grid_p4 = (n4 + block - 1) / block;                       // 4 pts/thread
    const int grid_4l = (int)(((long long)n * 4 + block - 1) / block);  // fallback
    const int nquads  = (n + 3) / 4;                                    // 4 pts/quad
    const int grid_q  = (int)(((long long)nquads * 4 + block - 1) / block);

    // workspace layout
    const size_t off_keys   = 0;
    const size_t off_rank   = off_keys + (size_t)n * 4;
    const size_t off_sorted = (off_rank + (size_t)n * 4 + 15) & ~(size_t)15;
    const size_t off_hist   = off_sorted + (size_t)n * 16;
    const size_t off_base   = off_hist + (size_t)NBINS * 4;
    const size_t need       = off_base + (size_t)NBINS * 4;

    if (ws_size < need) {
        k_main_plain<<<grid_4l, block, 0, stream>>>(pts, emb0, emb1, out, n);
        return;
    }

    char* ws = (char*)d_ws;
    unsigned* keys   = (unsigned*)(ws + off_keys);
    unsigned* rank   = (unsigned*)(ws + off_rank);
    floatx4*  sorted = (floatx4*)(ws + off_sorted);
    unsigned* hist   = (unsigned*)(ws + off_hist);
    unsigned* base   = (unsigned*)(ws + off_base);

    hipMemsetAsync(hist, 0, (size_t)NBINS * 4, stream);
    k_hist<<<grid_p4, block, 0, stream>>>(pts, n, keys, rank, hist);
    k_scan<<<1, SCAN_T, 0, stream>>>(hist, base);
    k_scatter<<<grid_p4, block, 0, stream>>>(pts, n, keys, rank, base, sorted);
    k_main_sorted<<<grid_q, block, 0, stream>>>(sorted, emb0, emb1, out, n);
}